// Round 10
// baseline (229.310 us; speedup 1.0000x reference)
//
#include <hip/hip_runtime.h>
#include <math.h>

#define SEQ 2048
#define NBATCH 2
#define DEMB 1024
#define NH 16
#define HD 64
#define NROWS (NBATCH * SEQ) // 4096

typedef __attribute__((ext_vector_type(8))) short short8;   // 8 bf16 (4 VGPR)
typedef __attribute__((ext_vector_type(4))) float f32x4;    // MFMA acc

__device__ __forceinline__ unsigned short f2bf(float f) {
    unsigned int u = __float_as_uint(f);
    u = (u + 0x7FFFu + ((u >> 16) & 1u)) >> 16;   // RNE
    return (unsigned short)u;
}
__device__ __forceinline__ unsigned short f2bf_fast(float f) {
    return (unsigned short)((__float_as_uint(f) + 0x8000u) >> 16); // round-half-up
}

// ============================================================================
// Cast fp32 inputs to bf16 (R2-proven). Wq pre-scaled by 0.125*log2(e) so
// attention softmax runs in the exp2 domain.
// ============================================================================
__global__ __launch_bounds__(256) void cast_bf16(
    const float* __restrict__ x, const float* __restrict__ wq,
    const float* __restrict__ wk, const float* __restrict__ wv,
    const float* __restrict__ wo,
    unsigned short* __restrict__ Xb, unsigned short* __restrict__ Wb,
    unsigned short* __restrict__ Wob)
{
    const int q = blockIdx.x * 256 + threadIdx.x; // quad index
    float4 v; unsigned short* dst; float sc = 1.f;
    if (q < 1048576) {                       // X: 4194304 elems
        v = ((const float4*)x)[q];
        dst = Xb + q * 4;
    } else if (q < 1835008) {                // Wq|Wk|Wv concat: 3145728 elems
        const int e = (q - 1048576) * 4;
        const int which = e >> 20;
        const int off = e & 1048575;
        const float* s = (which == 0) ? wq : (which == 1) ? wk : wv;
        v = *(const float4*)&s[off];
        sc = (which == 0) ? 0.18033688011112042f : 1.f;  // 0.125*log2(e)
        dst = Wb + e;
    } else {                                 // Wo: 1048576 elems
        const int j = q - 1835008;
        v = ((const float4*)wo)[j];
        dst = Wob + j * 4;
    }
    ushort4 o;
    o.x = f2bf(v.x * sc); o.y = f2bf(v.y * sc);
    o.z = f2bf(v.z * sc); o.w = f2bf(v.w * sc);
    *(ushort4*)dst = o;
}

// ============================================================================
// QKV GEMM (R9-proven): R2 reg-staged structure + fused V-transpose epilogue.
// A=Xb[4096][1024], B=Wb[3072][1024]. 128x128 tile, BK=32, 4 waves.
// Q,K written bf16 [b,h,s,d]; V written TRANSPOSED [b,h,d,s] via LDS.
// ============================================================================
__global__ __launch_bounds__(256) void gemm_qkv(
    const unsigned short* __restrict__ Xb, const unsigned short* __restrict__ Wb,
    unsigned short* __restrict__ Qb, unsigned short* __restrict__ Kb,
    unsigned short* __restrict__ Vtb)
{
    __shared__ __align__(16) short SM[8192];   // As = SM[0..4095], Bs = SM[4096..]
    short* const As = SM;
    short* const Bs = SM + 4096;

    const int tid = threadIdx.x;
    const int nblk = blockIdx.x;              // 0..23
    const int which = nblk >> 3;              // 0=Q 1=K 2=V
    const int n0c = (nblk & 7) * 128;         // col offset within one matrix
    const int m0 = blockIdx.y * 128;

    const int sr = tid >> 2, sg = tid & 3;
    const int slot = sg ^ ((sr >> 1) & 3);    // 2-way-free XOR swizzle
    const int st0 = sr * 32 + slot * 8;
    const int st1 = (sr + 64) * 32 + slot * 8;

    const int lane = tid & 63, w = tid >> 6;
    const int wr = w >> 1, wc = w & 1;
    const int fr = lane & 15, fq = lane >> 4;

    int offA[4], offB[4];
#pragma unroll
    for (int m = 0; m < 4; ++m) {
        const int rA = wr * 64 + m * 16 + fr;
        offA[m] = rA * 32 + ((fq ^ ((rA >> 1) & 3)) * 8);
        const int rB = wc * 64 + m * 16 + fr;
        offB[m] = rB * 32 + ((fq ^ ((rB >> 1) & 3)) * 8);
    }

    f32x4 acc[4][4];
#pragma unroll
    for (int m = 0; m < 4; ++m)
#pragma unroll
        for (int n = 0; n < 4; ++n) acc[m][n] = (f32x4){0.f, 0.f, 0.f, 0.f};

    const unsigned short* Wmat = Wb + (size_t)which * 1024 * 1024;
    const unsigned short* ga0 = Xb + (m0 + sr) * 1024 + sg * 8;
    const unsigned short* ga1 = Xb + (m0 + 64 + sr) * 1024 + sg * 8;
    const unsigned short* gb0 = Wmat + (n0c + sr) * 1024 + sg * 8;
    const unsigned short* gb1 = Wmat + (n0c + 64 + sr) * 1024 + sg * 8;

    short8 ra0 = *(const short8*)ga0, ra1 = *(const short8*)ga1;
    short8 rb0 = *(const short8*)gb0, rb1 = *(const short8*)gb1;

    for (int k = 0; k < 32; ++k) {
        __syncthreads();
        *(short8*)&As[st0] = ra0; *(short8*)&As[st1] = ra1;
        *(short8*)&Bs[st0] = rb0; *(short8*)&Bs[st1] = rb1;
        __syncthreads();
        if (k < 31) {
            ga0 += 32; ga1 += 32; gb0 += 32; gb1 += 32;
            ra0 = *(const short8*)ga0; ra1 = *(const short8*)ga1;
            rb0 = *(const short8*)gb0; rb1 = *(const short8*)gb1;
        }
        short8 af[4], bg[4];
#pragma unroll
        for (int m = 0; m < 4; ++m) af[m] = *(const short8*)&As[offA[m]];
#pragma unroll
        for (int n = 0; n < 4; ++n) bg[n] = *(const short8*)&Bs[offB[n]];
#pragma unroll
        for (int m = 0; m < 4; ++m)
#pragma unroll
            for (int n = 0; n < 4; ++n)
                acc[m][n] = __builtin_amdgcn_mfma_f32_16x16x32_bf16(
                    af[m], bg[n], acc[m][n], 0, 0, 0);
    }

    const int b_ = m0 >> 11;          // batch
    const int s_base = m0 & 2047;     // seq offset within batch

    if (which < 2) {
        // ---- Q/K epilogue: scalar stores to [b,h,s,d] ----
        unsigned short* Out = (which == 0) ? Qb : Kb;
#pragma unroll
        for (int n = 0; n < 4; ++n) {
            const int col = n0c + wc * 64 + n * 16 + fr;
            const int h = col >> 6;
            const int d = col & 63;
#pragma unroll
            for (int m = 0; m < 4; ++m) {
                const int srow = s_base + wr * 64 + m * 16 + fq * 4;
#pragma unroll
                for (int r = 0; r < 4; ++r)
                    Out[(((size_t)b_ * NH + h) * SEQ + srow + r) * HD + d] =
                        f2bf(acc[m][n][r]);
            }
        }
    } else {
        // ---- V epilogue: LDS transpose, write Vt [b,h,d,s] coalesced ----
        const int h0 = (n0c >> 6);    // first head of this tile (2 heads)
#pragma unroll
        for (int p = 0; p < 2; ++p) {
            __syncthreads();          // LDS free (K-loop reads / prev pass done)
            if (wc == p) {
#pragma unroll
                for (int n = 0; n < 4; ++n) {
                    const int dl = n * 16 + fr;           // 0..63 within pass
                    const int sw = (dl & 7) << 3;
#pragma unroll
                    for (int m = 0; m < 4; ++m) {
#pragma unroll
                        for (int r = 0; r < 4; ++r) {
                            const int s = wr * 64 + m * 16 + fq * 4 + r;
                            SM[dl * 128 + (s ^ sw)] = f2bf(acc[m][n][r]);
                        }
                    }
                }
            }
            __syncthreads();
            // read-out: wave w owns d-rows w*16..w*16+15; 16 lanes cover s
            unsigned short* dstbase =
                Vtb + (((size_t)b_ * NH + h0 + p) * HD) * SEQ;
#pragma unroll
            for (int i = 0; i < 4; ++i) {
                const int dl = w * 16 + i * 4 + fq;
                const short8 v = *(const short8*)&SM[dl * 128 + ((fr * 8) ^ ((dl & 7) << 3))];
                *(short8*)&dstbase[(size_t)dl * SEQ + s_base + fr * 8] = v;
            }
        }
    }
}

// ============================================================================
// MFMA flash attention v5: occupancy fix. 512 blocks x 4 waves (256 thr);
// one 128-row qt per block (16 qt x 32 bh) -> 2 blocks/CU, ~4 waves/SIMD,
// all waves active every staged tile. Per-wave math verbatim from the proven
// kernel (swapped QK^T, XOR-swizzled K/Vt staging, defer-max, exp2 domain).
// ============================================================================
__global__ __launch_bounds__(256) void flash_mfma5(
    const unsigned short* __restrict__ Qb, const unsigned short* __restrict__ Kb,
    const unsigned short* __restrict__ Vtb, unsigned short* __restrict__ ctx)
{
    __shared__ __align__(16) short Ks[64 * 64];
    __shared__ __align__(16) short Vs[64 * 64];     // Vt tile [d][kv]
    __shared__ __align__(16) short Ps[4 * 32 * 64]; // per-wave P [32 q][64 kv]

    const int qt = blockIdx.x;   // 0..15
    const int h  = blockIdx.y;
    const int b  = blockIdx.z;
    const size_t bh = (size_t)b * NH + h;
    const unsigned short* __restrict__ Qg = Qb  + bh * SEQ * HD;
    const unsigned short* __restrict__ Kg = Kb  + bh * SEQ * HD;
    const unsigned short* __restrict__ Vg = Vtb + bh * (size_t)HD * SEQ;

    const int tid = threadIdx.x;
    const int lane = tid & 63, w = tid >> 6;   // w = 0..3
    const int fr = lane & 15, fq = lane >> 4;

    const int qbase = qt * 128 + w * 32;
    const int qmaxw = qbase + 31;
    const int jstage = 2 * qt + 1;

    // staging: 256 threads cover 512 chunks of each 8KB tile (2 rows apart 32)
    const int sr0 = tid >> 3, sc = tid & 7;    // row 0..31, colgroup 0..7
    const int sr1 = sr0 + 32;
    const int ls0 = sr0 * 64 + ((sc * 8) ^ ((sr0 & 7) << 3));
    const int ls1 = ls0 + 32 * 64;             // same swizzle (row+32: &7 equal)

    short8 qa[2][2];
#pragma unroll
    for (int m = 0; m < 2; ++m)
#pragma unroll
        for (int ks = 0; ks < 2; ++ks)
            qa[m][ks] = *(const short8*)&Qg[(qbase + m * 16 + fr) * HD + ks * 32 + fq * 8];

    f32x4 o[2][4];
    float mold[2], lsum[2];
#pragma unroll
    for (int m = 0; m < 2; ++m) {
        mold[m] = -3e38f; lsum[m] = 0.f;
#pragma unroll
        for (int n = 0; n < 4; ++n) o[m][n] = (f32x4){0.f, 0.f, 0.f, 0.f};
    }

    short* const Pw = Ps + w * 2048;
    const int swz = (fr & 7) << 3;

    short8 kr0 = *(const short8*)&Kg[(size_t)sr0 * HD + sc * 8];
    short8 kr1 = *(const short8*)&Kg[(size_t)sr1 * HD + sc * 8];
    short8 vr0 = *(const short8*)&Vg[(size_t)sr0 * SEQ + sc * 8];
    short8 vr1 = *(const short8*)&Vg[(size_t)sr1 * SEQ + sc * 8];

    for (int j = 0; j <= jstage; ++j) {
        __syncthreads();
        *(short8*)&Ks[ls0] = kr0; *(short8*)&Ks[ls1] = kr1;
        *(short8*)&Vs[ls0] = vr0; *(short8*)&Vs[ls1] = vr1;
        __syncthreads();
        if (j < jstage) {
            kr0 = *(const short8*)&Kg[(size_t)((j + 1) * 64 + sr0) * HD + sc * 8];
            kr1 = *(const short8*)&Kg[(size_t)((j + 1) * 64 + sr1) * HD + sc * 8];
            vr0 = *(const short8*)&Vg[(size_t)sr0 * SEQ + (j + 1) * 64 + sc * 8];
            vr1 = *(const short8*)&Vg[(size_t)sr1 * SEQ + (j + 1) * 64 + sc * 8];
        }
        if (j * 64 > qmaxw) continue;   // last tile masked for lower waves

        f32x4 st[4][2];
#pragma unroll
        for (int n = 0; n < 4; ++n)
#pragma unroll
            for (int m = 0; m < 2; ++m) st[n][m] = (f32x4){0.f, 0.f, 0.f, 0.f};
#pragma unroll
        for (int ks = 0; ks < 2; ++ks) {
            short8 kf[4];
#pragma unroll
            for (int n = 0; n < 4; ++n) {
                const int row = n * 16 + fr;
                kf[n] = *(const short8*)&Ks[row * 64 + ((ks * 32 + fq * 8) ^ ((row & 7) << 3))];
            }
            __builtin_amdgcn_s_setprio(1);
#pragma unroll
            for (int n = 0; n < 4; ++n)
#pragma unroll
                for (int m = 0; m < 2; ++m)
                    st[n][m] = __builtin_amdgcn_mfma_f32_16x16x32_bf16(
                        kf[n], qa[m][ks], st[n][m], 0, 0, 0);
            __builtin_amdgcn_s_setprio(0);
        }

        if (j * 64 + 63 > qbase) {
#pragma unroll
            for (int n = 0; n < 4; ++n) {
                const int kv = j * 64 + n * 16 + fq * 4;
#pragma unroll
                for (int m = 0; m < 2; ++m) {
                    const int q = qbase + m * 16 + fr;
#pragma unroll
                    for (int r = 0; r < 4; ++r)
                        if (kv + r > q) st[n][m][r] = -3e38f;
                }
            }
        }

        float pmax[2];
#pragma unroll
        for (int m = 0; m < 2; ++m) {
            float t0 = fmaxf(fmaxf(st[0][m][0], st[0][m][1]), fmaxf(st[0][m][2], st[0][m][3]));
            float t1 = fmaxf(fmaxf(st[1][m][0], st[1][m][1]), fmaxf(st[1][m][2], st[1][m][3]));
            float t2 = fmaxf(fmaxf(st[2][m][0], st[2][m][1]), fmaxf(st[2][m][2], st[2][m][3]));
            float t3 = fmaxf(fmaxf(st[3][m][0], st[3][m][1]), fmaxf(st[3][m][2], st[3][m][3]));
            float t = fmaxf(fmaxf(t0, t1), fmaxf(t2, t3));
            t = fmaxf(t, __shfl_xor(t, 16));
            t = fmaxf(t, __shfl_xor(t, 32));
            pmax[m] = t;
        }

        const float growth = fmaxf(pmax[0] - mold[0], pmax[1] - mold[1]);
        if (!__all(growth <= 8.0f)) {
            float resc[2];
#pragma unroll
            for (int m = 0; m < 2; ++m) {
                const float nm = fmaxf(mold[m], pmax[m]);
                resc[m] = exp2f(mold[m] - nm);
                mold[m] = nm;
                lsum[m] *= resc[m];
            }
#pragma unroll
            for (int m = 0; m < 2; ++m)
#pragma unroll
                for (int rr = 0; rr < 4; ++rr) {
                    const float rsc = __shfl(resc[m], fq * 4 + rr);
#pragma unroll
                    for (int n = 0; n < 4; ++n) o[m][n][rr] *= rsc;
                }
        }

#pragma unroll
        for (int m = 0; m < 2; ++m) {
            float rs = 0.f;
            const int prow = m * 16 + fr;
#pragma unroll
            for (int n = 0; n < 4; ++n) {
                const float p0 = exp2f(st[n][m][0] - mold[m]);
                const float p1 = exp2f(st[n][m][1] - mold[m]);
                const float p2 = exp2f(st[n][m][2] - mold[m]);
                const float p3 = exp2f(st[n][m][3] - mold[m]);
                rs += (p0 + p1) + (p2 + p3);
                ushort4 pk;
                pk.x = f2bf_fast(p0); pk.y = f2bf_fast(p1);
                pk.z = f2bf_fast(p2); pk.w = f2bf_fast(p3);
                *(ushort4*)&Pw[prow * 64 + ((n * 16 + fq * 4) ^ swz)] = pk;
            }
            rs += __shfl_xor(rs, 16);
            rs += __shfl_xor(rs, 32);
            lsum[m] += rs;
        }

#pragma unroll
        for (int ks = 0; ks < 2; ++ks) {
            short8 pa[2], vb[4];
#pragma unroll
            for (int m = 0; m < 2; ++m) {
                const int row = m * 16 + fr;
                pa[m] = *(const short8*)&Pw[row * 64 + ((ks * 32 + fq * 8) ^ swz)];
            }
#pragma unroll
            for (int n = 0; n < 4; ++n) {
                const int row = n * 16 + fr;
                vb[n] = *(const short8*)&Vs[row * 64 + ((ks * 32 + fq * 8) ^ ((row & 7) << 3))];
            }
            __builtin_amdgcn_s_setprio(1);
#pragma unroll
            for (int m = 0; m < 2; ++m)
#pragma unroll
                for (int n = 0; n < 4; ++n)
                    o[m][n] = __builtin_amdgcn_mfma_f32_16x16x32_bf16(
                        pa[m], vb[n], o[m][n], 0, 0, 0);
            __builtin_amdgcn_s_setprio(0);
        }
    }

#pragma unroll
    for (int m = 0; m < 2; ++m)
#pragma unroll
        for (int rr = 0; rr < 4; ++rr) {
            const float lv = __shfl(lsum[m], fq * 4 + rr);
            const float inv = 1.f / lv;
            const int q = qbase + m * 16 + fq * 4 + rr;
            const size_t rowoff = ((size_t)b * SEQ + q) * DEMB + h * HD;
#pragma unroll
            for (int n = 0; n < 4; ++n)
                ctx[rowoff + n * 16 + fr] = f2bf(o[m][n][rr] * inv);
        }
}

// ============================================================================
// O-projection (R2-proven reg-staged): ctx_bf16 @ Wob^T + bo -> out fp32.
// ============================================================================
__global__ __launch_bounds__(256) void gemm_out(
    const unsigned short* __restrict__ Cb, const unsigned short* __restrict__ Wob,
    const float* __restrict__ bo, float* __restrict__ Out)
{
    __shared__ __align__(16) short As[128 * 32];
    __shared__ __align__(16) short Bs[128 * 32];

    const int tid = threadIdx.x;
    const int m0 = blockIdx.y * 128, n0 = blockIdx.x * 128;
    const int sr = tid >> 2, sg = tid & 3;
    const int slot = sg ^ ((sr >> 1) & 3);
    const int st0 = sr * 32 + slot * 8;
    const int st1 = (sr + 64) * 32 + slot * 8;

    const int lane = tid & 63, w = tid >> 6;
    const int wr = w >> 1, wc = w & 1;
    const int fr = lane & 15, fq = lane >> 4;

    int offA[4], offB[4];
#pragma unroll
    for (int m = 0; m < 4; ++m) {
        const int rA = wr * 64 + m * 16 + fr;
        offA[m] = rA * 32 + ((fq ^ ((rA >> 1) & 3)) * 8);
        const int rB = wc * 64 + m * 16 + fr;
        offB[m] = rB * 32 + ((fq ^ ((rB >> 1) & 3)) * 8);
    }

    f32x4 acc[4][4];
#pragma unroll
    for (int m = 0; m < 4; ++m)
#pragma unroll
        for (int n = 0; n < 4; ++n) acc[m][n] = (f32x4){0.f, 0.f, 0.f, 0.f};

    const unsigned short* ga0 = Cb + (m0 + sr) * 1024 + sg * 8;
    const unsigned short* ga1 = Cb + (m0 + 64 + sr) * 1024 + sg * 8;
    const unsigned short* gb0 = Wob + (n0 + sr) * 1024 + sg * 8;
    const unsigned short* gb1 = Wob + (n0 + 64 + sr) * 1024 + sg * 8;

    short8 ra0 = *(const short8*)ga0, ra1 = *(const short8*)ga1;
    short8 rb0 = *(const short8*)gb0, rb1 = *(const short8*)gb1;

    for (int k = 0; k < 32; ++k) {
        __syncthreads();
        *(short8*)&As[st0] = ra0; *(short8*)&As[st1] = ra1;
        *(short8*)&Bs[st0] = rb0; *(short8*)&Bs[st1] = rb1;
        __syncthreads();
        if (k < 31) {
            ga0 += 32; ga1 += 32; gb0 += 32; gb1 += 32;
            ra0 = *(const short8*)ga0; ra1 = *(const short8*)ga1;
            rb0 = *(const short8*)gb0; rb1 = *(const short8*)gb1;
        }
        short8 af[4], bg[4];
#pragma unroll
        for (int m = 0; m < 4; ++m) af[m] = *(const short8*)&As[offA[m]];
#pragma unroll
        for (int n = 0; n < 4; ++n) bg[n] = *(const short8*)&Bs[offB[n]];
#pragma unroll
        for (int m = 0; m < 4; ++m)
#pragma unroll
            for (int n = 0; n < 4; ++n)
                acc[m][n] = __builtin_amdgcn_mfma_f32_16x16x32_bf16(
                    af[m], bg[n], acc[m][n], 0, 0, 0);
    }

#pragma unroll
    for (int n = 0; n < 4; ++n) {
        const int col = n0 + wc * 64 + n * 16 + fr;
        const float bias = bo[col];
#pragma unroll
        for (int m = 0; m < 4; ++m) {
            const int rowb = m0 + wr * 64 + m * 16 + fq * 4;
#pragma unroll
            for (int r = 0; r < 4; ++r)
                Out[(size_t)(rowb + r) * DEMB + col] = acc[m][n][r] + bias;
        }
    }
}

extern "C" void kernel_launch(void* const* d_in, const int* in_sizes, int n_in,
                              void* d_out, int out_size, void* d_ws, size_t ws_size,
                              hipStream_t stream) {
    const float* x  = (const float*)d_in[0];
    const float* Wq = (const float*)d_in[1];
    const float* Wk = (const float*)d_in[2];
    const float* Wv = (const float*)d_in[3];
    const float* Wo = (const float*)d_in[4];
    const float* bo = (const float*)d_in[5];
    float* out = (float*)d_out;

    char* w = (char*)d_ws;
    const size_t MB = 1024 * 1024;
    unsigned short* Qb   = (unsigned short*)(w);            //  8 MB
    unsigned short* Kb   = (unsigned short*)(w + 8  * MB);  //  8 MB
    unsigned short* Vtb  = (unsigned short*)(w + 16 * MB);  //  8 MB [b,h,d,s]
    unsigned short* Cb   = (unsigned short*)(w + 24 * MB);  //  8 MB ctx
    unsigned short* Xb   = (unsigned short*)(w + 32 * MB);  //  8 MB
    unsigned short* Wb   = (unsigned short*)(w + 40 * MB);  //  6 MB (q|k|v)
    unsigned short* Wob  = (unsigned short*)(w + 46 * MB);  //  2 MB

    cast_bf16<<<8192, 256, 0, stream>>>(x, Wq, Wk, Wv, Wo, Xb, Wb, Wob);
    gemm_qkv<<<dim3(24, 32), 256, 0, stream>>>(Xb, Wb, Qb, Kb, Vtb);
    flash_mfma5<<<dim3(16, NH, NBATCH), 256, 0, stream>>>(Qb, Kb, Vtb, Cb);
    gemm_out<<<dim3(8, 32), 256, 0, stream>>>(Cb, Wob, bo, out);
}